// Round 1
// baseline (105.701 us; speedup 1.0000x reference)
//
#include <hip/hip_runtime.h>
#include <math.h>

#define NN 8
#define CC 96
#define HH 256
#define WW 256
#define GG 2
#define KK 3
#define CG (CC / GG)
#define HWD (HH * WW)

// ---------------------------------------------------------------------------
// Kernel 1: per-(n,c) mean over H*W.  One block per (n,c): 256 threads each
// read 64 float4 (256 floats) coalesced, then wave + LDS reduce.
// ---------------------------------------------------------------------------
__global__ __launch_bounds__(256) void mean_kernel(const float* __restrict__ x,
                                                   float* __restrict__ m) {
    const int b = blockIdx.x;  // 0 .. NN*CC-1
    const float4* xp = (const float4*)(x + (size_t)b * HWD);
    const int t = threadIdx.x;
    float s = 0.f;
#pragma unroll
    for (int i = 0; i < HWD / 4 / 256; ++i) {
        float4 v = xp[i * 256 + t];
        s += (v.x + v.y) + (v.z + v.w);
    }
    // wave64 reduce
#pragma unroll
    for (int off = 32; off; off >>= 1) s += __shfl_down(s, off, 64);
    __shared__ float ls[4];
    const int wid = t >> 6;
    if ((t & 63) == 0) ls[wid] = s;
    __syncthreads();
    if (t == 0) {
        float tot = (ls[0] + ls[1]) + (ls[2] + ls[3]);
        m[b] = tot * (1.0f / (float)HWD);
    }
}

// ---------------------------------------------------------------------------
// Kernel 2: filt[n, g, k] = tanh( dot(m[n, :], Wconv[g*K + k, :]) )
// 48 dot products of length 96 — one thread each.
// ---------------------------------------------------------------------------
__global__ void filt_kernel(const float* __restrict__ m,
                            const float* __restrict__ Wconv,
                            float* __restrict__ filt) {
    const int t = threadIdx.x;
    if (t >= NN * GG * KK) return;
    const int n = t / (GG * KK);
    const int gk = t % (GG * KK);
    float s = 0.f;
#pragma unroll
    for (int c = 0; c < CC; ++c) s += m[n * CC + c] * Wconv[gk * CC + c];
    filt[t] = tanhf(s);
}

// ---------------------------------------------------------------------------
// Kernel 3: fused main pass. One wave (64 lanes) owns one (n,c,h) row of 256
// floats: lane loads float4, row-mean (gap) via shfl_xor reduce, 3-tap
// reflect conv via shfl neighbors, affine epilogue, float4 store.
// 4 waves per block, no LDS, no barriers.
// ---------------------------------------------------------------------------
__global__ __launch_bounds__(256) void main_kernel(
    const float* __restrict__ x, const float* __restrict__ filt,
    const float* __restrict__ inside_all, const float* __restrict__ lamb_l,
    const float* __restrict__ lamb_h, float* __restrict__ out) {
    const int wave = threadIdx.x >> 6;
    const int lane = threadIdx.x & 63;
    const long long row = (long long)blockIdx.x * 4 + wave;  // 0 .. NN*CC*HH-1
    const int nc = (int)(row / HH);
    const int c = nc % CC;
    const int n = nc / CC;
    const int g = c / CG;

    const float* fr = filt + (n * GG + g) * KK;
    const float f0 = fr[0], f1 = fr[1], f2 = fr[2];
    const float ia = inside_all[c];
    const float ll = lamb_l[c];
    const float lh1 = lamb_h[c] + 1.0f;

    const size_t base = (size_t)row * WW;
    float4 v = ((const float4*)(x + base))[lane];

    // row sum -> gap (mean over width)
    float s = (v.x + v.y) + (v.z + v.w);
#pragma unroll
    for (int off = 1; off < 64; off <<= 1) s += __shfl_xor(s, off, 64);
    const float gap = s * (1.0f / (float)WW);

    // cross-lane neighbors: element j=4*lane+e needs x[j-1], x[j+1]
    const float left = __shfl_up(v.w, 1, 64);    // x[4*lane - 1]
    const float right = __shfl_down(v.x, 1, 64); // x[4*lane + 4]
    // reflect pad: x[-1] -> x[1] (= lane0 v.y); x[W] -> x[W-2] (= lane63 v.z)
    const float xm1 = (lane == 0) ? v.y : left;
    const float xp1 = (lane == 63) ? v.z : right;

    const float c0 = f0 * xm1 + f1 * v.x + f2 * v.y;
    const float c1 = f0 * v.x + f1 * v.y + f2 * v.z;
    const float c2 = f0 * v.y + f1 * v.z + f2 * v.w;
    const float c3 = f0 * v.z + f1 * v.w + f2 * xp1;

    const float a = ia + 1.0f;
    const float bterm = ia * gap;

    float4 o;
    o.x = (c0 * a - bterm) * ll + v.x * lh1;
    o.y = (c1 * a - bterm) * ll + v.y * lh1;
    o.z = (c2 * a - bterm) * ll + v.z * lh1;
    o.w = (c3 * a - bterm) * ll + v.w * lh1;
    ((float4*)(out + base))[lane] = o;
}

// ---------------------------------------------------------------------------
extern "C" void kernel_launch(void* const* d_in, const int* in_sizes, int n_in,
                              void* d_out, int out_size, void* d_ws,
                              size_t ws_size, hipStream_t stream) {
    const float* x = (const float*)d_in[0];
    const float* Wconv = (const float*)d_in[1];
    const float* inside_all = (const float*)d_in[2];
    const float* lamb_l = (const float*)d_in[3];
    const float* lamb_h = (const float*)d_in[4];
    float* out = (float*)d_out;

    float* m = (float*)d_ws;          // NN*CC floats
    float* filt = m + NN * CC;        // NN*GG*KK floats

    mean_kernel<<<NN * CC, 256, 0, stream>>>(x, m);
    filt_kernel<<<1, 64, 0, stream>>>(m, Wconv, filt);
    main_kernel<<<(NN * CC * HH) / 4, 256, 0, stream>>>(x, filt, inside_all,
                                                        lamb_l, lamb_h, out);
}

// Round 3
// 92.676 us; speedup vs baseline: 1.1405x; 1.1405x over previous
//
#include <hip/hip_runtime.h>
#include <math.h>

#define NN 8
#define CC 96
#define HH 256
#define WW 256
#define GG 2
#define KK 3
#define CG (CC / GG)
#define HWD (HH * WW)

typedef float fvec4 __attribute__((ext_vector_type(4)));

// ---------------------------------------------------------------------------
// Kernel 1: per-(n,c) mean over H*W.  One block per (n,c): 256 threads each
// read 64 float4 (256 floats) coalesced, then wave + LDS reduce.
// NORMAL loads on purpose: they allocate x into the 256 MiB Infinity Cache
// so the main pass re-reads hit L3.
// ---------------------------------------------------------------------------
__global__ __launch_bounds__(256) void mean_kernel(const float* __restrict__ x,
                                                   float* __restrict__ m) {
    const int b = blockIdx.x;  // 0 .. NN*CC-1
    const fvec4* xp = (const fvec4*)(x + (size_t)b * HWD);
    const int t = threadIdx.x;
    float s = 0.f;
#pragma unroll
    for (int i = 0; i < HWD / 4 / 256; ++i) {
        fvec4 v = xp[i * 256 + t];
        s += (v.x + v.y) + (v.z + v.w);
    }
    // wave64 reduce
#pragma unroll
    for (int off = 32; off; off >>= 1) s += __shfl_down(s, off, 64);
    __shared__ float ls[4];
    const int wid = t >> 6;
    if ((t & 63) == 0) ls[wid] = s;
    __syncthreads();
    if (t == 0) {
        float tot = (ls[0] + ls[1]) + (ls[2] + ls[3]);
        m[b] = tot * (1.0f / (float)HWD);
    }
}

// ---------------------------------------------------------------------------
// Kernel 2: filt[n, g, k] = tanh( dot(m[n, :], Wconv[g*K + k, :]) )
// 48 dot products of length 96 — one thread each.
// ---------------------------------------------------------------------------
__global__ void filt_kernel(const float* __restrict__ m,
                            const float* __restrict__ Wconv,
                            float* __restrict__ filt) {
    const int t = threadIdx.x;
    if (t >= NN * GG * KK) return;
    const int n = t / (GG * KK);
    const int gk = t % (GG * KK);
    float s = 0.f;
#pragma unroll
    for (int c = 0; c < CC; ++c) s += m[n * CC + c] * Wconv[gk * CC + c];
    filt[t] = tanhf(s);
}

// ---------------------------------------------------------------------------
// Kernel 3: fused main pass. One wave (64 lanes) owns one (n,c,h) row of 256
// floats: lane loads float4 (L3-hit expected), row-mean (gap) via shfl_xor
// reduce, 3-tap reflect conv via shfl neighbors, affine epilogue,
// NON-TEMPORAL float4 store (don't let `out` evict x from L3).
// ---------------------------------------------------------------------------
__global__ __launch_bounds__(256) void main_kernel(
    const float* __restrict__ x, const float* __restrict__ filt,
    const float* __restrict__ inside_all, const float* __restrict__ lamb_l,
    const float* __restrict__ lamb_h, float* __restrict__ out) {
    const int wave = threadIdx.x >> 6;
    const int lane = threadIdx.x & 63;
    // 64 blocks per (n,c): each block = 4 rows, all within one (n,c)
    const int nc = blockIdx.x >> 6;
    const int row_in_nc = ((blockIdx.x & 63) << 2) + wave;
    const int c = nc % CC;
    const int n = nc / CC;
    const int g = c / CG;

    const float* fr = filt + (n * GG + g) * KK;
    const float f0 = fr[0], f1 = fr[1], f2 = fr[2];
    const float ia = inside_all[c];
    const float ll = lamb_l[c];
    const float lh1 = lamb_h[c] + 1.0f;

    const size_t base = ((size_t)nc * HH + row_in_nc) * WW;
    fvec4 v = ((const fvec4*)(x + base))[lane];

    // row sum -> gap (mean over width)
    float s = (v.x + v.y) + (v.z + v.w);
#pragma unroll
    for (int off = 1; off < 64; off <<= 1) s += __shfl_xor(s, off, 64);
    const float gap = s * (1.0f / (float)WW);

    // cross-lane neighbors: element j=4*lane+e needs x[j-1], x[j+1]
    const float left = __shfl_up(v.w, 1, 64);    // x[4*lane - 1]
    const float right = __shfl_down(v.x, 1, 64); // x[4*lane + 4]
    // reflect pad: x[-1] -> x[1] (= lane0 v.y); x[W] -> x[W-2] (= lane63 v.z)
    const float xm1 = (lane == 0) ? v.y : left;
    const float xp1 = (lane == 63) ? v.z : right;

    const float c0 = f0 * xm1 + f1 * v.x + f2 * v.y;
    const float c1 = f0 * v.x + f1 * v.y + f2 * v.z;
    const float c2 = f0 * v.y + f1 * v.z + f2 * v.w;
    const float c3 = f0 * v.z + f1 * v.w + f2 * xp1;

    const float a = ia + 1.0f;
    const float bterm = ia * gap;

    fvec4 o;
    o.x = (c0 * a - bterm) * ll + v.x * lh1;
    o.y = (c1 * a - bterm) * ll + v.y * lh1;
    o.z = (c2 * a - bterm) * ll + v.z * lh1;
    o.w = (c3 * a - bterm) * ll + v.w * lh1;
    __builtin_nontemporal_store(o, (fvec4*)(out + base) + lane);
}

// ---------------------------------------------------------------------------
extern "C" void kernel_launch(void* const* d_in, const int* in_sizes, int n_in,
                              void* d_out, int out_size, void* d_ws,
                              size_t ws_size, hipStream_t stream) {
    const float* x = (const float*)d_in[0];
    const float* Wconv = (const float*)d_in[1];
    const float* inside_all = (const float*)d_in[2];
    const float* lamb_l = (const float*)d_in[3];
    const float* lamb_h = (const float*)d_in[4];
    float* out = (float*)d_out;

    float* m = (float*)d_ws;          // NN*CC floats
    float* filt = m + NN * CC;        // NN*GG*KK floats

    mean_kernel<<<NN * CC, 256, 0, stream>>>(x, m);
    filt_kernel<<<1, 64, 0, stream>>>(m, Wconv, filt);
    main_kernel<<<(NN * CC * HH) / 4, 256, 0, stream>>>(x, filt, inside_all,
                                                        lamb_l, lamb_h, out);
}